// Round 6
// baseline (84.135 us; speedup 1.0000x reference)
//
#include <hip/hip_runtime.h>

// PartialMatchingLoss: mean over (b,m) of min_n ||partial[b,m] - completed[b,n]||
// B=8, M=4096 (partial), N=8192 (completed), D=3, fp32.
//
// f(n) = 0.5*||c||^2 - p.c. n's processed in PACKED pairs via v_pk_fma_f32:
// 3 pk_fma + 1 v_min3_f32 per 2 n's per point = 2.0 instr-slots/pair.
// R6 delta vs R5: __launch_bounds__(NT,2) (the (NT,4) 128-VGPR cap bought
// nothing — grid is 512 blocks = 2 blocks/CU, grid-limited — but risked
// spills with the f2 splats) and k-loop unroll 4 -> 2 (halve live c regs).

typedef float f2 __attribute__((ext_vector_type(2)));

constexpr int B  = 8;
constexpr int N  = 8192;           // completed points per batch
constexpr int M  = 4096;           // partial points per batch
constexpr int NT = 256;            // threads per block (main)
constexpr int TP = 8;              // partial points per thread
constexpr int MBLK = NT * TP;      // 2048
constexpr int MC   = M / MBLK;     // 2
constexpr int NBLK = 256;          // completed points per block (= NT)
constexpr int NC   = N / NBLK;     // 32 n-chunks
constexpr int ROWS = B * M;        // 32768 (b,m) rows
constexpr float FMAX = 3.402823466e38f;

__global__ __launch_bounds__(NT, 2) void pml_main(const float* __restrict__ completed,
                                                  const float* __restrict__ partial,
                                                  float* __restrict__ ws,
                                                  float* __restrict__ out) {
    // SoA pair layout: csx[k] = (c[2k].x, c[2k+1].x) etc. -> packed operands
    // read as single ds_read_b64 each. 4 KB total.
    __shared__ f2 csx[NBLK / 2], csy[NBLK / 2], csz[NBLK / 2], csw[NBLK / 2];

    const int t     = threadIdx.x;
    const int b     = blockIdx.z;
    const int mBase = blockIdx.y * MBLK;
    const int nBase = blockIdx.x * NBLK;

    if (blockIdx.x == 0 && blockIdx.y == 0 && b == 0 && t == 0)
        out[0] = 0.0f;   // reduce kernel runs strictly after this one

    {
        const float* cp = completed + (size_t)(b * N + nBase + t) * 3;
        float x = cp[0], y = cp[1], z = cp[2];
        ((float*)csx)[t] = x;                      // flat index t == n-index
        ((float*)csy)[t] = y;                      // 2-way bank alias: free
        ((float*)csz)[t] = z;
        ((float*)csw)[t] = 0.5f * (x * x + y * y + z * z);
    }
    __syncthreads();

    const int m0 = mBase + t * TP;
    // 8 points * 12 B = 96 B per thread, 16B-aligned -> 6 float4 loads.
    const float4* pv = (const float4*)(partial + (size_t)(b * M + m0) * 3);
    float4 v0 = pv[0], v1 = pv[1], v2 = pv[2], v3 = pv[3], v4 = pv[4], v5 = pv[5];

    float px[TP], py[TP], pz[TP];
    px[0] = v0.x; py[0] = v0.y; pz[0] = v0.z;
    px[1] = v0.w; py[1] = v1.x; pz[1] = v1.y;
    px[2] = v1.z; py[2] = v1.w; pz[2] = v2.x;
    px[3] = v2.y; py[3] = v2.z; pz[3] = v2.w;
    px[4] = v3.x; py[4] = v3.y; pz[4] = v3.z;
    px[5] = v3.w; py[5] = v4.x; pz[5] = v4.y;
    px[6] = v4.z; py[6] = v4.w; pz[6] = v5.x;
    px[7] = v5.y; py[7] = v5.z; pz[7] = v5.w;

    // Pre-splatted negated coords (loop-invariant packed operands).
    f2 nx[TP], ny[TP], nz[TP];
    float fm[TP];
#pragma unroll
    for (int p = 0; p < TP; ++p) {
        nx[p] = (f2){-px[p], -px[p]};
        ny[p] = (f2){-py[p], -py[p]};
        nz[p] = (f2){-pz[p], -pz[p]};
        fm[p] = FMAX;
    }

#pragma unroll 2
    for (int k = 0; k < NBLK / 2; ++k) {           // each k covers 2 n's
        f2 cx = csx[k];   // wave-uniform -> broadcast, conflict-free
        f2 cy = csy[k];
        f2 cz = csz[k];
        f2 cw = csw[k];
#pragma unroll
        for (int p = 0; p < TP; ++p) {
            f2 f = __builtin_elementwise_fma(
                       nx[p], cx,
                       __builtin_elementwise_fma(
                           ny[p], cy,
                           __builtin_elementwise_fma(nz[p], cz, cw)));
            fm[p] = fminf(fm[p], fminf(f.x, f.y)); // v_min3_f32
        }
    }

    // store per-chunk f_min (d2 / sqrt deferred to reduce pass)
    float4* wsv = (float4*)(ws + (size_t)blockIdx.x * ROWS + b * M + m0);
    wsv[0] = make_float4(fm[0], fm[1], fm[2], fm[3]);
    wsv[1] = make_float4(fm[4], fm[5], fm[6], fm[7]);
}

constexpr int RT = 256;
constexpr int RBLOCKS = ROWS / RT;   // 128

__global__ __launch_bounds__(RT) void pml_reduce(const float* __restrict__ ws,
                                                 const float* __restrict__ partial,
                                                 float* __restrict__ out) {
    const int row = blockIdx.x * RT + threadIdx.x;   // = b*M + m, coalesced
    float m = FMAX;
#pragma unroll
    for (int c = 0; c < NC; c += 2) {                // v_min3_f32 pairing
        float f0 = ws[(size_t)c * ROWS + row];
        float f1 = ws[(size_t)(c + 1) * ROWS + row];
        m = fminf(m, fminf(f0, f1));
    }

    const float* pp = partial + (size_t)row * 3;
    float x = pp[0], y = pp[1], z = pp[2];
    float psq = x * x + y * y + z * z;
    float d2  = fmaxf(fmaf(2.0f, m, psq), 0.0f);
    float s   = sqrtf(d2);

#pragma unroll
    for (int off = 32; off > 0; off >>= 1) s += __shfl_down(s, off);

    __shared__ float red[RT / 64];
    const int lane = threadIdx.x & 63;
    const int wid  = threadIdx.x >> 6;
    if (lane == 0) red[wid] = s;
    __syncthreads();
    if (threadIdx.x == 0) {
        float tot = red[0] + red[1] + red[2] + red[3];
        atomicAdd(out, tot * (1.0f / (float)ROWS));
    }
}

extern "C" void kernel_launch(void* const* d_in, const int* in_sizes, int n_in,
                              void* d_out, int out_size, void* d_ws, size_t ws_size,
                              hipStream_t stream) {
    const float* completed = (const float*)d_in[0];  // (8, 8192, 3)
    const float* partial   = (const float*)d_in[1];  // (8, 4096, 3)
    float* out = (float*)d_out;
    float* ws  = (float*)d_ws;   // uses NC * ROWS * 4 = 4 MB

    dim3 grid(NC, MC, B);        // (32, 2, 8) = 512 blocks, 2 blocks/CU
    pml_main<<<grid, NT, 0, stream>>>(completed, partial, ws, out);
    pml_reduce<<<RBLOCKS, RT, 0, stream>>>(ws, partial, out);
}

// Round 7
// 79.538 us; speedup vs baseline: 1.0578x; 1.0578x over previous
//
#include <hip/hip_runtime.h>

// PartialMatchingLoss: mean over (b,m) of min_n ||partial[b,m] - completed[b,n]||
// B=8, M=4096 (partial), N=8192 (completed), D=3, fp32.
//
// f(n) = 0.5*||c||^2 - p.c  (3 FMA per pair); n's processed in pairs,
// fminf(fm, fminf(f0,f1)) -> v_min3_f32: 3.5 VALU ops/pair.
// This is the best-measured config (R4, 80.07 us): 512 blocks, 4 MB ws,
// scalar FMA (packed fp32 is NOT double-rate on CDNA4 — scalar v_fma_f32
// already issues at the 157 TF rate), unroll 4, lb(NT,4).
// R5 (packed f2) was neutral; R6 (unroll 2, lb(NT,2)) regressed -3.4 us (ILP).

constexpr int B  = 8;
constexpr int N  = 8192;           // completed points per batch
constexpr int M  = 4096;           // partial points per batch
constexpr int NT = 256;            // threads per block (main)
constexpr int TP = 8;              // partial points per thread
constexpr int MBLK = NT * TP;      // 2048
constexpr int MC   = M / MBLK;     // 2
constexpr int NBLK = 256;          // completed points per block (= NT, branchless stage)
constexpr int NC   = N / NBLK;     // 32 n-chunks
constexpr int ROWS = B * M;        // 32768 (b,m) rows
constexpr float FMAX = 3.402823466e38f;

__global__ __launch_bounds__(NT, 4) void pml_main(const float* __restrict__ completed,
                                                  const float* __restrict__ partial,
                                                  float* __restrict__ ws,
                                                  float* __restrict__ out) {
    __shared__ float4 cs[NBLK];
    const int t     = threadIdx.x;
    const int b     = blockIdx.z;
    const int mBase = blockIdx.y * MBLK;
    const int nBase = blockIdx.x * NBLK;

    if (blockIdx.x == 0 && blockIdx.y == 0 && b == 0 && t == 0)
        out[0] = 0.0f;   // reduce kernel runs strictly after this one

    // Branchless stage: every thread loads one completed point.
    {
        const float* cp = completed + (size_t)(b * N + nBase + t) * 3;
        float x = cp[0], y = cp[1], z = cp[2];
        cs[t] = make_float4(x, y, z, 0.5f * (x * x + y * y + z * z));
    }
    __syncthreads();

    const int m0 = mBase + t * TP;
    // 8 points * 12 B = 96 B per thread, 16B-aligned -> 6 float4 loads.
    const float4* pv = (const float4*)(partial + (size_t)(b * M + m0) * 3);
    float4 v0 = pv[0], v1 = pv[1], v2 = pv[2], v3 = pv[3], v4 = pv[4], v5 = pv[5];

    float nx[TP], ny[TP], nz[TP], fm[TP];
    nx[0] = -v0.x; ny[0] = -v0.y; nz[0] = -v0.z;
    nx[1] = -v0.w; ny[1] = -v1.x; nz[1] = -v1.y;
    nx[2] = -v1.z; ny[2] = -v1.w; nz[2] = -v2.x;
    nx[3] = -v2.y; ny[3] = -v2.z; nz[3] = -v2.w;
    nx[4] = -v3.x; ny[4] = -v3.y; nz[4] = -v3.z;
    nx[5] = -v3.w; ny[5] = -v4.x; nz[5] = -v4.y;
    nx[6] = -v4.z; ny[6] = -v4.w; nz[6] = -v5.x;
    nx[7] = -v5.y; ny[7] = -v5.z; nz[7] = -v5.w;
#pragma unroll
    for (int p = 0; p < TP; ++p) fm[p] = FMAX;

#pragma unroll 4
    for (int j = 0; j < NBLK; j += 2) {
        float4 c0 = cs[j];       // wave-uniform -> LDS broadcast, conflict-free
        float4 c1 = cs[j + 1];
#pragma unroll
        for (int p = 0; p < TP; ++p) {
            float f0 = fmaf(nx[p], c0.x, fmaf(ny[p], c0.y, fmaf(nz[p], c0.z, c0.w)));
            float f1 = fmaf(nx[p], c1.x, fmaf(ny[p], c1.y, fmaf(nz[p], c1.z, c1.w)));
            fm[p] = fminf(fm[p], fminf(f0, f1));   // v_min3_f32
        }
    }

    // store per-chunk f_min (d2 / sqrt deferred to reduce pass)
    float4* wsv = (float4*)(ws + (size_t)blockIdx.x * ROWS + b * M + m0);
    wsv[0] = make_float4(fm[0], fm[1], fm[2], fm[3]);
    wsv[1] = make_float4(fm[4], fm[5], fm[6], fm[7]);
}

constexpr int RT = 256;
constexpr int RBLOCKS = ROWS / RT;   // 128

__global__ __launch_bounds__(RT) void pml_reduce(const float* __restrict__ ws,
                                                 const float* __restrict__ partial,
                                                 float* __restrict__ out) {
    const int row = blockIdx.x * RT + threadIdx.x;   // = b*M + m, coalesced
    float m0 = FMAX, m1 = FMAX;
#pragma unroll
    for (int c = 0; c < NC; c += 2) {               // min3 pairing here too
        float f0 = ws[(size_t)c * ROWS + row];
        float f1 = ws[(size_t)(c + 1) * ROWS + row];
        m0 = fminf(m0, fminf(f0, f1));
    }
    float m = fminf(m0, m1);

    const float* pp = partial + (size_t)row * 3;
    float x = pp[0], y = pp[1], z = pp[2];
    float psq = x * x + y * y + z * z;
    float d2  = fmaxf(fmaf(2.0f, m, psq), 0.0f);
    float s   = sqrtf(d2);

#pragma unroll
    for (int off = 32; off > 0; off >>= 1) s += __shfl_down(s, off);

    __shared__ float red[RT / 64];
    const int lane = threadIdx.x & 63;
    const int wid  = threadIdx.x >> 6;
    if (lane == 0) red[wid] = s;
    __syncthreads();
    if (threadIdx.x == 0) {
        float tot = red[0] + red[1] + red[2] + red[3];
        atomicAdd(out, tot * (1.0f / (float)ROWS));
    }
}

extern "C" void kernel_launch(void* const* d_in, const int* in_sizes, int n_in,
                              void* d_out, int out_size, void* d_ws, size_t ws_size,
                              hipStream_t stream) {
    const float* completed = (const float*)d_in[0];  // (8, 8192, 3)
    const float* partial   = (const float*)d_in[1];  // (8, 4096, 3)
    float* out = (float*)d_out;
    float* ws  = (float*)d_ws;   // uses NC * ROWS * 4 = 4 MB

    dim3 grid(NC, MC, B);        // (32, 2, 8) = 512 blocks, 2 blocks/CU
    pml_main<<<grid, NT, 0, stream>>>(completed, partial, ws, out);
    pml_reduce<<<RBLOCKS, RT, 0, stream>>>(ws, partial, out);
}